// Round 1
// baseline (5001.049 us; speedup 1.0000x reference)
//
#include <hip/hip_runtime.h>
#include <math.h>

// Problem constants
#define EE 1024
#define DD 768
#define BB 64
#define NQQ 64
#define NHH 16
#define NPP 4
#define ROWS_TOT 784   // 576 + 144 + 64

// ---------------------------------------------------------------------------
// Generic fp32 tiled GEMM: C[M,N] = A' @ B' + bias
//   MODE 0: A is plain row-major [M,K]
//   MODE 2: A rows are 2x2 feature blocks gathered from features[B,576,768]
//   MODE 3: A rows are 3x3 feature blocks gathered from features
//   BT true:  B is weight layout [N,K] row-major  (C = A @ W^T)
//   BT false: B is [K,N] row-major                (C = A @ B)
// C row remap for value tensor: if Rl>0, crow = (m/Rl)*crowStride + crowOff + m%Rl
// ---------------------------------------------------------------------------
template<int MODE>
__device__ __forceinline__ float loadA(const float* __restrict__ A, int m, int k, int K) {
    if constexpr (MODE == 0) {
        return A[(size_t)m * K + k];
    } else {
        constexpr int gw = (MODE == 2) ? 12 : 8;
        constexpr int Rl = gw * gw;
        int b = m / Rl;
        int rl = m - b * Rl;
        int s = k / 768;
        int within = k - s * 768;
        int bi = rl / gw, bj = rl - bi * gw;
        int di = s / MODE, dj = s - di * MODE;
        int src = (MODE * bi + di) * 24 + MODE * bj + dj;
        return A[((size_t)(b * 576 + src)) * 768 + within];
    }
}

template<int MODE, bool BT>
__global__ __launch_bounds__(256) void gemm_tile(
    const float* __restrict__ A, const float* __restrict__ Bm,
    const float* __restrict__ bias, float* __restrict__ C,
    int M, int N, int K, int Rl, int crowStride, int crowOff)
{
    __shared__ float As[32][65];
    __shared__ float Bs[32][65];
    const int t = threadIdx.x;
    const int m0 = blockIdx.y * 64, n0 = blockIdx.x * 64;
    float acc[4][4] = {{0.f}};
    const int tm = (t >> 4) << 2;
    const int tn = (t & 15) << 2;

    for (int k0 = 0; k0 < K; k0 += 32) {
#pragma unroll
        for (int i = 0; i < 8; ++i) {
            int idx = t + i * 256;
            int r = idx >> 5, kk = idx & 31;
            As[kk][r] = loadA<MODE>(A, m0 + r, k0 + kk, K);
        }
#pragma unroll
        for (int i = 0; i < 8; ++i) {
            int idx = t + i * 256;
            if constexpr (BT) {
                int n = idx >> 5, kk = idx & 31;
                Bs[kk][n] = Bm[(size_t)(n0 + n) * K + (k0 + kk)];
            } else {
                int kk = idx >> 6, n = idx & 63;
                Bs[kk][n] = Bm[(size_t)(k0 + kk) * N + (n0 + n)];
            }
        }
        __syncthreads();
#pragma unroll
        for (int kk = 0; kk < 32; ++kk) {
            float a[4], b[4];
#pragma unroll
            for (int i = 0; i < 4; ++i) a[i] = As[kk][tm + i];
#pragma unroll
            for (int j = 0; j < 4; ++j) b[j] = Bs[kk][tn + j];
#pragma unroll
            for (int i = 0; i < 4; ++i)
#pragma unroll
                for (int j = 0; j < 4; ++j)
                    acc[i][j] += a[i] * b[j];
        }
        __syncthreads();
    }

#pragma unroll
    for (int i = 0; i < 4; ++i) {
        int m = m0 + tm + i;
        int crow;
        if (Rl > 0) crow = (m / Rl) * crowStride + crowOff + (m % Rl);
        else        crow = m;
#pragma unroll
        for (int j = 0; j < 4; ++j) {
            int n = n0 + tn + j;
            float v = acc[i][j];
            if (bias) v += bias[n];
            C[(size_t)crow * N + n] = v;
        }
    }
}

// b'[e] = sum_j vp_w[e,j]*pb[j] + vp_b[e]   (1024 outputs, one wave each)
__global__ void fused_bias_kernel(const float* __restrict__ vp_w, const float* __restrict__ vp_b,
                                  const float* __restrict__ pb, float* __restrict__ bout)
{
    int e = blockIdx.x * 4 + (threadIdx.x >> 6);
    int lane = threadIdx.x & 63;
    float s = 0.f;
    for (int k = lane; k < EE; k += 64) s += vp_w[(size_t)e * EE + k] * pb[k];
#pragma unroll
    for (int o = 32; o > 0; o >>= 1) s += __shfl_down(s, o, 64);
    if (lane == 0) bout[e] = s + vp_b[e];
}

// ---------------------------------------------------------------------------
// Query branch (batch-independent), all fp64 to match np reference indexing
// ---------------------------------------------------------------------------
__global__ void rg1_kernel(const float* __restrict__ qe, const float* __restrict__ w,
                           const float* __restrict__ b, double* __restrict__ h0)
{
    int o = blockIdx.x * 4 + (threadIdx.x >> 6);   // 0..65535 = q*1024+n
    int lane = threadIdx.x & 63;
    int q = o >> 10, n = o & 1023;
    double s = 0.0;
    for (int k = lane; k < EE; k += 64)
        s += (double)qe[q * EE + k] * (double)w[(size_t)n * EE + k];
#pragma unroll
    for (int off = 32; off > 0; off >>= 1) s += __shfl_down(s, off, 64);
    if (lane == 0) h0[o] = s + (double)b[n];
}

__global__ void ln_gelu_kernel(const double* __restrict__ h0, const float* __restrict__ g,
                               const float* __restrict__ bb, double* __restrict__ h)
{
    __shared__ double red[256];
    __shared__ double stats[2];
    int q = blockIdx.x, t = threadIdx.x;
    double x[4];
#pragma unroll
    for (int i = 0; i < 4; ++i) x[i] = h0[q * 1024 + t + i * 256];
    double s = x[0] + x[1] + x[2] + x[3];
    red[t] = s; __syncthreads();
    for (int o = 128; o; o >>= 1) { if (t < o) red[t] += red[t + o]; __syncthreads(); }
    if (t == 0) stats[0] = red[0] / 1024.0;
    __syncthreads();
    double mean = stats[0];
    double d = 0.0;
#pragma unroll
    for (int i = 0; i < 4; ++i) { double dd = x[i] - mean; d += dd * dd; }
    red[t] = d; __syncthreads();
    for (int o = 128; o; o >>= 1) { if (t < o) red[t] += red[t + o]; __syncthreads(); }
    if (t == 0) stats[1] = red[0] / 1024.0;
    __syncthreads();
    double inv = 1.0 / sqrt(stats[1] + 1e-5);
#pragma unroll
    for (int i = 0; i < 4; ++i) {
        int c = t + i * 256;
        double y = (x[i] - mean) * inv * (double)g[c] + (double)bb[c];
        h[q * 1024 + c] = y * 0.5 * (1.0 + erf(y * 0.70710678118654752440));
    }
}

__global__ void rp_kernel(const double* __restrict__ h, const float* __restrict__ w2,
                          const float* __restrict__ b2, double* __restrict__ rp)
{
    int o = blockIdx.x * 4 + (threadIdx.x >> 6);   // 0..127 = q*2+r
    int lane = threadIdx.x & 63;
    int q = o >> 1, r = o & 1;
    double s = 0.0;
    for (int k = lane; k < EE; k += 64)
        s += h[q * 1024 + k] * (double)w2[r * 1024 + k];
#pragma unroll
    for (int off = 32; off > 0; off >>= 1) s += __shfl_down(s, off, 64);
    if (lane == 0) rp[o] = 1.0 / (1.0 + exp(-(s + (double)b2[r])));
}

__global__ void offidx_kernel(const float* __restrict__ qe, const float* __restrict__ so_w,
                              const float* __restrict__ so_b, const float* __restrict__ aw_w,
                              const float* __restrict__ aw_b, const double* __restrict__ rp,
                              float* __restrict__ awf, int* __restrict__ idxv)
{
    __shared__ double offv[128];
    __shared__ double logit[64];
    int q = blockIdx.x, t = threadIdx.x;
    if (t < 128) {
        double s = 0.0;
        for (int k = 0; k < EE; ++k) s += (double)qe[q * EE + k] * (double)so_w[(size_t)t * EE + k];
        offv[t] = s + (double)so_b[t];
    } else if (t < 192) {
        int n = t - 128;
        double s = 0.0;
        for (int k = 0; k < EE; ++k) s += (double)qe[q * EE + k] * (double)aw_w[(size_t)n * EE + k];
        logit[n] = s + (double)aw_b[n];
    }
    __syncthreads();
    if (t < 64) {
        int hh = t >> 2, p = t & 3;
        double l0 = logit[hh * 4 + 0], l1 = logit[hh * 4 + 1];
        double l2 = logit[hh * 4 + 2], l3 = logit[hh * 4 + 3];
        double m = fmax(fmax(l0, l1), fmax(l2, l3));
        double den = exp(l0 - m) + exp(l1 - m) + exp(l2 - m) + exp(l3 - m);
        awf[(q * 16 + hh) * 4 + p] = (float)(exp(logit[hh * 4 + p] - m) / den);
        const int Wss[3] = {24, 12, 8};
        const int starts[3] = {0, 576, 720};
        double ox = offv[(hh * 4 + p) * 2 + 0], oy = offv[(hh * 4 + p) * 2 + 1];
        double rx = rp[q * 2 + 0], ry = rp[q * 2 + 1];
#pragma unroll
        for (int l = 0; l < 3; ++l) {
            int Ws = Wss[l];
            double sx = rx + ox; sx = sx < 0.0 ? 0.0 : (sx > 1.0 ? 1.0 : sx);
            double sy = ry + oy; sy = sy < 0.0 ? 0.0 : (sy > 1.0 ? 1.0 : sy);
            int x0 = (int)floor(sx * (double)(Ws - 1));
            int y0 = (int)floor(sy * (double)(Ws - 1));
            idxv[((l * 64 + q) * 16 + hh) * 4 + p] = starts[l] + y0 * Ws + x0;
        }
    }
}

// out0[b,q,h,:] = sum_{l,p} aw[q,h,p] * value[b, idx[l,q,h,p], h, :]
__global__ void gather_kernel(const float* __restrict__ value, const float* __restrict__ awf,
                              const int* __restrict__ idxv, float* __restrict__ out0)
{
    int unit = blockIdx.x * 4 + (threadIdx.x >> 6);  // b*1024 + q*16 + h
    int lane = threadIdx.x & 63;
    int b = unit >> 10;
    int rem = unit & 1023;
    int q = rem >> 4, h = rem & 15;
    float acc = 0.f;
#pragma unroll
    for (int l = 0; l < 3; ++l)
#pragma unroll
        for (int p = 0; p < 4; ++p) {
            int row = idxv[((l * 64 + q) * 16 + h) * 4 + p];
            float w = awf[(q * 16 + h) * 4 + p];
            acc += w * value[((size_t)(b * ROWS_TOT + row) * 16 + h) * 64 + lane];
        }
    out0[((size_t)(b * 64 + q) * 16 + h) * 64 + lane] = acc;
}

// final fp32 LayerNorm over E=1024 per row
__global__ void ln_kernel(const float* __restrict__ x, const float* __restrict__ g,
                          const float* __restrict__ bb, float* __restrict__ y)
{
    __shared__ float red[256];
    __shared__ float stats[2];
    int r = blockIdx.x, t = threadIdx.x;
    float v[4];
#pragma unroll
    for (int i = 0; i < 4; ++i) v[i] = x[(size_t)r * 1024 + t + i * 256];
    float s = v[0] + v[1] + v[2] + v[3];
    red[t] = s; __syncthreads();
    for (int o = 128; o; o >>= 1) { if (t < o) red[t] += red[t + o]; __syncthreads(); }
    if (t == 0) stats[0] = red[0] / 1024.f;
    __syncthreads();
    float mean = stats[0];
    float d = 0.f;
#pragma unroll
    for (int i = 0; i < 4; ++i) { float dd = v[i] - mean; d += dd * dd; }
    red[t] = d; __syncthreads();
    for (int o = 128; o; o >>= 1) { if (t < o) red[t] += red[t + o]; __syncthreads(); }
    if (t == 0) stats[1] = red[0] / 1024.f;
    __syncthreads();
    float inv = 1.f / sqrtf(stats[1] + 1e-5f);
#pragma unroll
    for (int i = 0; i < 4; ++i) {
        int c = t + i * 256;
        y[(size_t)r * 1024 + c] = (v[i] - mean) * inv * g[c] + bb[c];
    }
}

extern "C" void kernel_launch(void* const* d_in, const int* in_sizes, int n_in,
                              void* d_out, int out_size, void* d_ws, size_t ws_size,
                              hipStream_t stream)
{
    const float* features  = (const float*)d_in[0];
    const float* p1_w      = (const float*)d_in[1];
    const float* p1_b      = (const float*)d_in[2];
    const float* p2_w      = (const float*)d_in[3];
    const float* p2_b      = (const float*)d_in[4];
    const float* p3_w      = (const float*)d_in[5];
    const float* p3_b      = (const float*)d_in[6];
    const float* query_emb = (const float*)d_in[7];
    const float* rg_w1     = (const float*)d_in[8];
    const float* rg_b1     = (const float*)d_in[9];
    const float* rg_g      = (const float*)d_in[10];
    const float* rg_b      = (const float*)d_in[11];
    const float* rg_w2     = (const float*)d_in[12];
    const float* rg_b2     = (const float*)d_in[13];
    const float* so_w      = (const float*)d_in[14];
    const float* so_b      = (const float*)d_in[15];
    const float* aw_w      = (const float*)d_in[16];
    const float* aw_b      = (const float*)d_in[17];
    const float* vp_w      = (const float*)d_in[18];
    const float* vp_b      = (const float*)d_in[19];
    const float* op_w      = (const float*)d_in[20];
    const float* op_b      = (const float*)d_in[21];
    const float* fln_g     = (const float*)d_in[22];
    const float* fln_b     = (const float*)d_in[23];
    const float* fin_w     = (const float*)d_in[24];
    const float* fin_b     = (const float*)d_in[25];
    float* out = (float*)d_out;

    // workspace layout (floats unless noted)
    float* ws    = (float*)d_ws;
    float* W1p   = ws;                       // 1024*768
    float* W2p   = W1p + 786432;             // 1024*3072
    float* W3p   = W2p + 3145728;            // 1024*6912
    float* b1p   = W3p + 7077888;            // 1024
    float* b2p   = b1p + 1024;
    float* b3p   = b2p + 1024;
    float* value = b3p + 1024;               // 64*784*1024
    float* out0  = value + 51380224;         // 4096*1024
    float* out1  = out0 + 4194304;           // 4096*1024
    float* awf   = out1 + 4194304;           // 4096
    int*   idxv  = (int*)(awf + 4096);       // 3*64*16*4
    double* h0   = (double*)(idxv + 12288);  // 64*1024
    double* hb   = h0 + 65536;               // 64*1024
    double* rp   = hb + 65536;               // 128

    dim3 blk(256);

    // ---- fused weights: Wl' = vp_w @ pl_w ; bl' = vp_w @ pl_b + vp_b ----
    gemm_tile<0, false><<<dim3(12, 16),  blk, 0, stream>>>(vp_w, p1_w, nullptr, W1p, 1024, 768,  1024, 0, 0, 0);
    gemm_tile<0, false><<<dim3(48, 16),  blk, 0, stream>>>(vp_w, p2_w, nullptr, W2p, 1024, 3072, 1024, 0, 0, 0);
    gemm_tile<0, false><<<dim3(108, 16), blk, 0, stream>>>(vp_w, p3_w, nullptr, W3p, 1024, 6912, 1024, 0, 0, 0);
    fused_bias_kernel<<<256, blk, 0, stream>>>(vp_w, vp_b, p1_b, b1p);
    fused_bias_kernel<<<256, blk, 0, stream>>>(vp_w, vp_b, p2_b, b2p);
    fused_bias_kernel<<<256, blk, 0, stream>>>(vp_w, vp_b, p3_b, b3p);

    // ---- query branch (fp64, batch-independent) ----
    rg1_kernel<<<16384, blk, 0, stream>>>(query_emb, rg_w1, rg_b1, h0);
    ln_gelu_kernel<<<64, blk, 0, stream>>>(h0, rg_g, rg_b, hb);
    rp_kernel<<<32, blk, 0, stream>>>(hb, rg_w2, rg_b2, rp);
    offidx_kernel<<<64, blk, 0, stream>>>(query_emb, so_w, so_b, aw_w, aw_b, rp, awf, idxv);

    // ---- value tensor, fused projection per level ----
    gemm_tile<0, true><<<dim3(16, 576), blk, 0, stream>>>(features, W1p, b1p, value, 36864, 1024, 768,  576, ROWS_TOT, 0);
    gemm_tile<2, true><<<dim3(16, 144), blk, 0, stream>>>(features, W2p, b2p, value, 9216,  1024, 3072, 144, ROWS_TOT, 576);
    gemm_tile<3, true><<<dim3(16, 64),  blk, 0, stream>>>(features, W3p, b3p, value, 4096,  1024, 6912, 64,  ROWS_TOT, 720);

    // ---- deformable gather + attention-weight combine ----
    gather_kernel<<<16384, blk, 0, stream>>>(value, awf, idxv, out0);

    // ---- output projection, LN, final projection ----
    gemm_tile<0, true><<<dim3(16, 64), blk, 0, stream>>>(out0, op_w, op_b, out1, 4096, 1024, 1024, 0, 0, 0);
    ln_kernel<<<4096, blk, 0, stream>>>(out1, fln_g, fln_b, out0);
    gemm_tile<0, true><<<dim3(16, 64), blk, 0, stream>>>(out0, fin_w, fin_b, out, 4096, 1024, 1024, 0, 0, 0);
}

// Round 2
// 799.643 us; speedup vs baseline: 6.2541x; 6.2541x over previous
//
#include <hip/hip_runtime.h>
#include <math.h>

#define EE 1024
#define ROWS_TOT 784   // 576 + 144 + 64

typedef __attribute__((ext_vector_type(4))) float f4;
typedef __attribute__((ext_vector_type(4))) float f32x4;
typedef __attribute__((ext_vector_type(8))) __bf16 bf16x8;
typedef __attribute__((ext_vector_type(8))) unsigned short ushort8;

__device__ __forceinline__ unsigned short f2b(float x) {
    unsigned int u = __float_as_uint(x);
    unsigned int r = (u + 0x7fffu + ((u >> 16) & 1u)) >> 16;
    return (unsigned short)r;
}
__device__ __forceinline__ float b2f(unsigned short u) {
    unsigned int v = ((unsigned int)u) << 16;
    return __uint_as_float(v);
}

__device__ __forceinline__ void gload16(const unsigned short* g, unsigned short* l) {
    __builtin_amdgcn_global_load_lds(
        (const __attribute__((address_space(1))) unsigned int*)g,
        (__attribute__((address_space(3))) unsigned int*)l,
        16, 0, 0);
}

// ---------------------------------------------------------------------------
// bf16 MFMA GEMM: C[M,N] = A[M,K] @ B[N,K]^T + bias
// 128x128 tile, BK=32, 4 waves, 16x16x32 MFMA, global_load_lds staging.
// Row remap: if Rl>0, crow = (m/Rl)*crowStride + crowOff + m%Rl
// ---------------------------------------------------------------------------
template<bool OB>
__global__ __launch_bounds__(256) void gemm_bf16(
    const unsigned short* __restrict__ A, const unsigned short* __restrict__ Bw,
    const float* __restrict__ bias, void* __restrict__ Cv,
    int M, int N, int K, int Rl, int crowStride, int crowOff)
{
    __shared__ unsigned short As[128 * 32];
    __shared__ unsigned short Bs[128 * 32];
    const int t = threadIdx.x;
    const int lane = t & 63;
    const int w = t >> 6;
    const int wm = w >> 1, wn = w & 1;

    // bijective XCD swizzle (all grids have nwg % 8 == 0)
    int nwg = gridDim.x * gridDim.y;
    int bid = blockIdx.y * gridDim.x + blockIdx.x;
    int chunk = nwg >> 3;
    int swz = (bid & 7) * chunk + (bid >> 3);
    int by = swz / gridDim.x, bx = swz % gridDim.x;
    const int m0 = by * 128, n0 = bx * 128;

    f32x4 acc[4][4] = {};

    const int sr = lane >> 2;          // row within 16-row issue
    const int sc = lane & 3;           // 8-elem col group
    const unsigned short* gA0 = A + (size_t)(m0 + (w * 2) * 16 + sr) * K + sc * 8;
    const unsigned short* gA1 = A + (size_t)(m0 + (w * 2 + 1) * 16 + sr) * K + sc * 8;
    const unsigned short* gB0 = Bw + (size_t)(n0 + (w * 2) * 16 + sr) * K + sc * 8;
    const unsigned short* gB1 = Bw + (size_t)(n0 + (w * 2 + 1) * 16 + sr) * K + sc * 8;
    unsigned short* lA0 = &As[(w * 2) * 512];
    unsigned short* lA1 = &As[(w * 2 + 1) * 512];
    unsigned short* lB0 = &Bs[(w * 2) * 512];
    unsigned short* lB1 = &Bs[(w * 2 + 1) * 512];

    const int fr = lane & 15;          // fragment row/col
    const int kg = lane >> 4;          // k-group
    const unsigned short* rdA = &As[(wm * 64 + fr) * 32 + kg * 8];
    const unsigned short* rdB = &Bs[(wn * 64 + fr) * 32 + kg * 8];

    for (int k0 = 0; k0 < K; k0 += 32) {
        gload16(gA0 + k0, lA0);
        gload16(gA1 + k0, lA1);
        gload16(gB0 + k0, lB0);
        gload16(gB1 + k0, lB1);
        __syncthreads();
        bf16x8 af[4], bfr[4];
#pragma unroll
        for (int i = 0; i < 4; ++i) af[i]  = *(const bf16x8*)(rdA + i * 512);
#pragma unroll
        for (int j = 0; j < 4; ++j) bfr[j] = *(const bf16x8*)(rdB + j * 512);
#pragma unroll
        for (int i = 0; i < 4; ++i)
#pragma unroll
            for (int j = 0; j < 4; ++j)
                acc[i][j] = __builtin_amdgcn_mfma_f32_16x16x32_bf16(af[i], bfr[j], acc[i][j], 0, 0, 0);
        __syncthreads();
    }

#pragma unroll
    for (int i = 0; i < 4; ++i) {
#pragma unroll
        for (int r = 0; r < 4; ++r) {
            int m = m0 + wm * 64 + i * 16 + kg * 4 + r;
            int crow = (Rl > 0) ? (m / Rl) * crowStride + crowOff + (m % Rl) : m;
#pragma unroll
            for (int j = 0; j < 4; ++j) {
                int n = n0 + wn * 64 + j * 16 + fr;
                float v = acc[i][j][r];
                if (bias) v += bias[n];
                if (OB) ((unsigned short*)Cv)[(size_t)crow * N + n] = f2b(v);
                else    ((float*)Cv)[(size_t)crow * N + n] = v;
            }
        }
    }
}

// fp32 -> bf16 straight copy (n divisible by 2048)
__global__ void f2b_kernel(const float* __restrict__ in, unsigned short* __restrict__ out) {
    size_t i = ((size_t)blockIdx.x * 256 + threadIdx.x) * 8;
    f4 a = *(const f4*)(in + i);
    f4 b = *(const f4*)(in + i + 4);
    ushort8 o;
    o[0] = f2b(a[0]); o[1] = f2b(a[1]); o[2] = f2b(a[2]); o[3] = f2b(a[3]);
    o[4] = f2b(b[0]); o[5] = f2b(b[1]); o[6] = f2b(b[2]); o[7] = f2b(b[3]);
    *(ushort8*)(out + i) = o;
}

// features [B,576,768] fp32 -> rearranged [B*Rl, MODE*MODE*768] bf16
template<int MODE>
__global__ void feat_rearr(const float* __restrict__ F, unsigned short* __restrict__ out) {
    constexpr int gw = 24 / MODE, Rl = gw * gw, K = MODE * MODE * 768;
    size_t e0 = ((size_t)blockIdx.x * 256 + threadIdx.x) * 8;
    int m = (int)(e0 / K);
    int k = (int)(e0 % K);
    int b = m / Rl, rl = m % Rl;
    int bi = rl / gw, bj = rl % gw;
    int s = k / 768, within = k % 768;
    int di = s / MODE, dj = s % MODE;
    int src = (MODE * bi + di) * 24 + MODE * bj + dj;
    const float* ptr = F + ((size_t)(b * 576 + src)) * 768 + within;
    f4 a = *(const f4*)ptr;
    f4 c = *(const f4*)(ptr + 4);
    ushort8 o;
    o[0] = f2b(a[0]); o[1] = f2b(a[1]); o[2] = f2b(a[2]); o[3] = f2b(a[3]);
    o[4] = f2b(c[0]); o[5] = f2b(c[1]); o[6] = f2b(c[2]); o[7] = f2b(c[3]);
    *(ushort8*)(out + e0) = o;
}

// transpose-convert: in fp32 [R,C] -> out bf16 [C,R]
__global__ void tconv_kernel(const float* __restrict__ in, unsigned short* __restrict__ out,
                             int R, int C) {
    __shared__ float tile[32][33];
    int c0 = blockIdx.x * 32, r0 = blockIdx.y * 32;
    int tx = threadIdx.x & 31, ty = threadIdx.x >> 5;   // ty 0..7
#pragma unroll
    for (int i = 0; i < 32; i += 8)
        tile[ty + i][tx] = in[(size_t)(r0 + ty + i) * C + c0 + tx];
    __syncthreads();
#pragma unroll
    for (int i = 0; i < 32; i += 8)
        out[(size_t)(c0 + ty + i) * R + r0 + tx] = f2b(tile[tx][ty + i]);
}

// b'[e] = sum_j vp_w[e,j]*pb[j] + vp_b[e]
__global__ void fused_bias_kernel(const float* __restrict__ vp_w, const float* __restrict__ vp_b,
                                  const float* __restrict__ pb, float* __restrict__ bout)
{
    int e = blockIdx.x * 4 + (threadIdx.x >> 6);
    int lane = threadIdx.x & 63;
    float s = 0.f;
    for (int k = lane; k < EE; k += 64) s += vp_w[(size_t)e * EE + k] * pb[k];
#pragma unroll
    for (int o = 32; o > 0; o >>= 1) s += __shfl_down(s, o, 64);
    if (lane == 0) bout[e] = s + vp_b[e];
}

// ---------------------------------------------------------------------------
// Query branch (batch-independent), fp64 to match np reference indexing
// ---------------------------------------------------------------------------
__global__ void rg1_kernel(const float* __restrict__ qe, const float* __restrict__ w,
                           const float* __restrict__ b, double* __restrict__ h0)
{
    int o = blockIdx.x * 4 + (threadIdx.x >> 6);
    int lane = threadIdx.x & 63;
    int q = o >> 10, n = o & 1023;
    double s = 0.0;
    for (int k = lane; k < EE; k += 64)
        s += (double)qe[q * EE + k] * (double)w[(size_t)n * EE + k];
#pragma unroll
    for (int off = 32; off > 0; off >>= 1) s += __shfl_down(s, off, 64);
    if (lane == 0) h0[o] = s + (double)b[n];
}

__global__ void ln_gelu_kernel(const double* __restrict__ h0, const float* __restrict__ g,
                               const float* __restrict__ bb, double* __restrict__ h)
{
    __shared__ double red[256];
    __shared__ double stats[2];
    int q = blockIdx.x, t = threadIdx.x;
    double x[4];
#pragma unroll
    for (int i = 0; i < 4; ++i) x[i] = h0[q * 1024 + t + i * 256];
    double s = x[0] + x[1] + x[2] + x[3];
    red[t] = s; __syncthreads();
    for (int o = 128; o; o >>= 1) { if (t < o) red[t] += red[t + o]; __syncthreads(); }
    if (t == 0) stats[0] = red[0] / 1024.0;
    __syncthreads();
    double mean = stats[0];
    double d = 0.0;
#pragma unroll
    for (int i = 0; i < 4; ++i) { double dd = x[i] - mean; d += dd * dd; }
    red[t] = d; __syncthreads();
    for (int o = 128; o; o >>= 1) { if (t < o) red[t] += red[t + o]; __syncthreads(); }
    if (t == 0) stats[1] = red[0] / 1024.0;
    __syncthreads();
    double inv = 1.0 / sqrt(stats[1] + 1e-5);
#pragma unroll
    for (int i = 0; i < 4; ++i) {
        int c = t + i * 256;
        double y = (x[i] - mean) * inv * (double)g[c] + (double)bb[c];
        h[q * 1024 + c] = y * 0.5 * (1.0 + erf(y * 0.70710678118654752440));
    }
}

__global__ void rp_kernel(const double* __restrict__ h, const float* __restrict__ w2,
                          const float* __restrict__ b2, double* __restrict__ rp)
{
    int o = blockIdx.x * 4 + (threadIdx.x >> 6);
    int lane = threadIdx.x & 63;
    int q = o >> 1, r = o & 1;
    double s = 0.0;
    for (int k = lane; k < EE; k += 64)
        s += h[q * 1024 + k] * (double)w2[r * 1024 + k];
#pragma unroll
    for (int off = 32; off > 0; off >>= 1) s += __shfl_down(s, off, 64);
    if (lane == 0) rp[o] = 1.0 / (1.0 + exp(-(s + (double)b2[r])));
}

__global__ void offidx_kernel(const float* __restrict__ qe, const float* __restrict__ so_w,
                              const float* __restrict__ so_b, const float* __restrict__ aw_w,
                              const float* __restrict__ aw_b, const double* __restrict__ rp,
                              float* __restrict__ awf, int* __restrict__ idxv)
{
    __shared__ double offv[128];
    __shared__ double logit[64];
    int q = blockIdx.x, t = threadIdx.x;
    if (t < 128) {
        double s = 0.0;
        for (int k = 0; k < EE; ++k) s += (double)qe[q * EE + k] * (double)so_w[(size_t)t * EE + k];
        offv[t] = s + (double)so_b[t];
    } else if (t < 192) {
        int n = t - 128;
        double s = 0.0;
        for (int k = 0; k < EE; ++k) s += (double)qe[q * EE + k] * (double)aw_w[(size_t)n * EE + k];
        logit[n] = s + (double)aw_b[n];
    }
    __syncthreads();
    if (t < 64) {
        int hh = t >> 2, p = t & 3;
        double l0 = logit[hh * 4 + 0], l1 = logit[hh * 4 + 1];
        double l2 = logit[hh * 4 + 2], l3 = logit[hh * 4 + 3];
        double m = fmax(fmax(l0, l1), fmax(l2, l3));
        double den = exp(l0 - m) + exp(l1 - m) + exp(l2 - m) + exp(l3 - m);
        awf[(q * 16 + hh) * 4 + p] = (float)(exp(logit[hh * 4 + p] - m) / den);
        const int Wss[3] = {24, 12, 8};
        const int starts[3] = {0, 576, 720};
        double ox = offv[(hh * 4 + p) * 2 + 0], oy = offv[(hh * 4 + p) * 2 + 1];
        double rx = rp[q * 2 + 0], ry = rp[q * 2 + 1];
#pragma unroll
        for (int l = 0; l < 3; ++l) {
            int Ws = Wss[l];
            double sx = rx + ox; sx = sx < 0.0 ? 0.0 : (sx > 1.0 ? 1.0 : sx);
            double sy = ry + oy; sy = sy < 0.0 ? 0.0 : (sy > 1.0 ? 1.0 : sy);
            int x0 = (int)floor(sx * (double)(Ws - 1));
            int y0 = (int)floor(sy * (double)(Ws - 1));
            idxv[((l * 64 + q) * 16 + hh) * 4 + p] = starts[l] + y0 * Ws + x0;
        }
    }
}

// out0[b,q,h,:] = sum_{l,p} aw[q,h,p] * value[b, idx[l,q,h,p], h, :]   (bf16 in/out)
__global__ void gather_kernel(const unsigned short* __restrict__ value, const float* __restrict__ awf,
                              const int* __restrict__ idxv, unsigned short* __restrict__ out0)
{
    int unit = blockIdx.x * 4 + (threadIdx.x >> 6);
    int lane = threadIdx.x & 63;
    int b = unit >> 10;
    int rem = unit & 1023;
    int q = rem >> 4, h = rem & 15;
    float acc = 0.f;
#pragma unroll
    for (int l = 0; l < 3; ++l)
#pragma unroll
        for (int p = 0; p < 4; ++p) {
            int row = idxv[((l * 64 + q) * 16 + h) * 4 + p];
            float wgt = awf[(q * 16 + h) * 4 + p];
            acc += wgt * b2f(value[((size_t)(b * ROWS_TOT + row)) * 1024 + h * 64 + lane]);
        }
    out0[((size_t)(b * 64 + q)) * 1024 + h * 64 + lane] = f2b(acc);
}

// fp32 LayerNorm over 1024, output bf16
__global__ void ln_bf16_kernel(const float* __restrict__ x, const float* __restrict__ g,
                               const float* __restrict__ bb, unsigned short* __restrict__ y)
{
    __shared__ float red[256];
    __shared__ float stats[2];
    int r = blockIdx.x, t = threadIdx.x;
    float v[4];
#pragma unroll
    for (int i = 0; i < 4; ++i) v[i] = x[(size_t)r * 1024 + t + i * 256];
    float s = v[0] + v[1] + v[2] + v[3];
    red[t] = s; __syncthreads();
    for (int o = 128; o; o >>= 1) { if (t < o) red[t] += red[t + o]; __syncthreads(); }
    if (t == 0) stats[0] = red[0] / 1024.f;
    __syncthreads();
    float mean = stats[0];
    float d = 0.f;
#pragma unroll
    for (int i = 0; i < 4; ++i) { float dd = v[i] - mean; d += dd * dd; }
    red[t] = d; __syncthreads();
    for (int o = 128; o; o >>= 1) { if (t < o) red[t] += red[t + o]; __syncthreads(); }
    if (t == 0) stats[1] = red[0] / 1024.f;
    __syncthreads();
    float inv = 1.f / sqrtf(stats[1] + 1e-5f);
#pragma unroll
    for (int i = 0; i < 4; ++i) {
        int c = t + i * 256;
        y[(size_t)r * 1024 + c] = f2b((v[i] - mean) * inv * g[c] + bb[c]);
    }
}

extern "C" void kernel_launch(void* const* d_in, const int* in_sizes, int n_in,
                              void* d_out, int out_size, void* d_ws, size_t ws_size,
                              hipStream_t stream)
{
    const float* features  = (const float*)d_in[0];
    const float* p1_w      = (const float*)d_in[1];
    const float* p1_b      = (const float*)d_in[2];
    const float* p2_w      = (const float*)d_in[3];
    const float* p2_b      = (const float*)d_in[4];
    const float* p3_w      = (const float*)d_in[5];
    const float* p3_b      = (const float*)d_in[6];
    const float* query_emb = (const float*)d_in[7];
    const float* rg_w1     = (const float*)d_in[8];
    const float* rg_b1     = (const float*)d_in[9];
    const float* rg_g      = (const float*)d_in[10];
    const float* rg_b      = (const float*)d_in[11];
    const float* rg_w2     = (const float*)d_in[12];
    const float* rg_b2     = (const float*)d_in[13];
    const float* so_w      = (const float*)d_in[14];
    const float* so_b      = (const float*)d_in[15];
    const float* aw_w      = (const float*)d_in[16];
    const float* aw_b      = (const float*)d_in[17];
    const float* vp_w      = (const float*)d_in[18];
    const float* vp_b      = (const float*)d_in[19];
    const float* op_w      = (const float*)d_in[20];
    const float* op_b      = (const float*)d_in[21];
    const float* fln_g     = (const float*)d_in[22];
    const float* fln_b     = (const float*)d_in[23];
    const float* fin_w     = (const float*)d_in[24];
    const float* fin_b     = (const float*)d_in[25];
    float* out = (float*)d_out;

    // ---- workspace layout (bytes) ----
    char* p = (char*)d_ws;
    unsigned short* FEAT = (unsigned short*)p; p += 56623104;   // reused per level
    unsigned short* PT   = (unsigned short*)p; p += 14155776;   // p_w transposed (largest: p3)
    unsigned short* WW   = (unsigned short*)p; p += 14155776;   // fused weight (largest: W3)
    unsigned short* VPW  = (unsigned short*)p; p += 2097152;
    unsigned short* VAL  = (unsigned short*)p; p += 102760448;  // value bf16 [64*784,1024]
    unsigned short* OUT0 = (unsigned short*)p; p += 8388608;
    float*          OUT1 = (float*)p;          p += 16777216;
    unsigned short* LNO  = (unsigned short*)p; p += 8388608;
    unsigned short* OPW  = (unsigned short*)p; p += 2097152;
    unsigned short* FINW = (unsigned short*)p; p += 2097152;
    float* b1p  = (float*)p; p += 4096;
    float* b2p  = (float*)p; p += 4096;
    float* b3p  = (float*)p; p += 4096;
    float* awf  = (float*)p; p += 16384;
    int*   idxv = (int*)p;   p += 49152;
    double* h0  = (double*)p; p += 524288;
    double* hb  = (double*)p; p += 524288;
    double* rp  = (double*)p; p += 1024;

    dim3 blk(256);

    // ---- query branch (fp64, batch-independent) ----
    rg1_kernel<<<16384, blk, 0, stream>>>(query_emb, rg_w1, rg_b1, h0);
    ln_gelu_kernel<<<64, blk, 0, stream>>>(h0, rg_g, rg_b, hb);
    rp_kernel<<<32, blk, 0, stream>>>(hb, rg_w2, rg_b2, rp);
    offidx_kernel<<<64, blk, 0, stream>>>(query_emb, so_w, so_b, aw_w, aw_b, rp, awf, idxv);

    // ---- conversions independent of level loop ----
    f2b_kernel<<<512, blk, 0, stream>>>(vp_w, VPW);
    f2b_kernel<<<512, blk, 0, stream>>>(op_w, OPW);
    f2b_kernel<<<512, blk, 0, stream>>>(fin_w, FINW);
    fused_bias_kernel<<<256, blk, 0, stream>>>(vp_w, vp_b, p1_b, b1p);
    fused_bias_kernel<<<256, blk, 0, stream>>>(vp_w, vp_b, p2_b, b2p);
    fused_bias_kernel<<<256, blk, 0, stream>>>(vp_w, vp_b, p3_b, b3p);

    // ---- level 3: W3' = vp_w @ p3_w [1024,6912]; value rows 720..783 ----
    tconv_kernel<<<dim3(216, 32), blk, 0, stream>>>(p3_w, PT, 1024, 6912);
    gemm_bf16<true><<<dim3(54, 8), blk, 0, stream>>>(VPW, PT, nullptr, WW, 1024, 6912, 1024, 0, 0, 0);
    feat_rearr<3><<<13824, blk, 0, stream>>>(features, FEAT);
    gemm_bf16<true><<<dim3(8, 32), blk, 0, stream>>>(FEAT, WW, b3p, VAL, 4096, 1024, 6912, 64, ROWS_TOT, 720);

    // ---- level 2 ----
    tconv_kernel<<<dim3(96, 32), blk, 0, stream>>>(p2_w, PT, 1024, 3072);
    gemm_bf16<true><<<dim3(24, 8), blk, 0, stream>>>(VPW, PT, nullptr, WW, 1024, 3072, 1024, 0, 0, 0);
    feat_rearr<2><<<13824, blk, 0, stream>>>(features, FEAT);
    gemm_bf16<true><<<dim3(8, 72), blk, 0, stream>>>(FEAT, WW, b2p, VAL, 9216, 1024, 3072, 144, ROWS_TOT, 576);

    // ---- level 1 ----
    tconv_kernel<<<dim3(24, 32), blk, 0, stream>>>(p1_w, PT, 1024, 768);
    gemm_bf16<true><<<dim3(6, 8), blk, 0, stream>>>(VPW, PT, nullptr, WW, 1024, 768, 1024, 0, 0, 0);
    f2b_kernel<<<13824, blk, 0, stream>>>(features, FEAT);
    gemm_bf16<true><<<dim3(8, 288), blk, 0, stream>>>(FEAT, WW, b1p, VAL, 36864, 1024, 768, 576, ROWS_TOT, 0);

    // ---- deformable gather ----
    gather_kernel<<<16384, blk, 0, stream>>>(VAL, awf, idxv, OUT0);

    // ---- output projection, LN, final projection ----
    gemm_bf16<false><<<dim3(8, 32), blk, 0, stream>>>(OUT0, OPW, op_b, OUT1, 4096, 1024, 1024, 0, 0, 0);
    ln_bf16_kernel<<<4096, blk, 0, stream>>>(OUT1, fln_g, fln_b, LNO);
    gemm_bf16<false><<<dim3(8, 32), blk, 0, stream>>>(LNO, FINW, fin_b, out, 4096, 1024, 1024, 0, 0, 0);
}